// Round 1
// baseline (6797.362 us; speedup 1.0000x reference)
//
#include <hip/hip_runtime.h>
#include <math.h>

#define N_EDGES   1048576
#define N_CENTERS 32768
#define N_SPECIES 4
#define N_BASIS   12
#define N_MAX     8
// out[c*512 + L*32 + s*8 + n], L in [0,16)

__global__ __launch_bounds__(256) void sph_exp_kernel(
    const float* __restrict__ vectors,
    const float* __restrict__ rw,        // (4,12,8)
    const int*   __restrict__ cidx,
    const int*   __restrict__ sidx,
    float*       __restrict__ out)
{
    __shared__ float sW[4 * N_BASIS * N_MAX];   // 384 floats
    for (int i = threadIdx.x; i < 384; i += 256) sW[i] = rw[i];
    __syncthreads();

    const int e = blockIdx.x * 256 + threadIdx.x;
    if (e >= N_EDGES) return;

    float x = vectors[3 * e + 0];
    float y = vectors[3 * e + 1];
    float z = vectors[3 * e + 2];

    const float r2    = x * x + y * y + z * z + 1e-12f;
    const float inv_r = rsqrtf(r2);
    const float r     = r2 * inv_r;
    x *= inv_r; y *= inv_r; z *= inv_r;

    // radial basis: phi[b] = sin(pi/R_CUT * r * (b+1)) / r * (1/sqrt(32))
    float phi[N_BASIS];
    const float t = 0.6283185307179586f * r;          // pi/5 * r
    const float scale = 0.17677669529663687f * inv_r; // NORM / r
    #pragma unroll
    for (int b = 0; b < N_BASIS; ++b)
        phi[b] = sinf(t * (float)(b + 1)) * scale;

    // real spherical harmonics, l<=3
    const float x2 = x * x, y2 = y * y, z2 = z * z;
    float sh[16];
    sh[0]  = 0.28209479177387814f;
    sh[1]  = 0.4886025119029199f * y;
    sh[2]  = 0.4886025119029199f * z;
    sh[3]  = 0.4886025119029199f * x;
    sh[4]  = 1.0925484305920792f * x * y;
    sh[5]  = 1.0925484305920792f * y * z;
    sh[6]  = 0.31539156525252005f * (3.0f * z2 - 1.0f);
    sh[7]  = 1.0925484305920792f * x * z;
    sh[8]  = 0.5462742152960396f * (x2 - y2);
    sh[9]  = 0.5900435899266435f * y * (3.0f * x2 - y2);
    sh[10] = 2.890611442640554f  * x * y * z;
    sh[11] = 0.4570457994644658f * y * (5.0f * z2 - 1.0f);
    sh[12] = 0.3731763325901154f * (5.0f * z2 * z - 3.0f * z);
    sh[13] = 0.4570457994644658f * x * (5.0f * z2 - 1.0f);
    sh[14] = 1.445305721320277f  * z * (x2 - y2);
    sh[15] = 0.5900435899266435f * x * (x2 - y2);

    // rad[l][n] = sum_b phi[b] * W[l][b][n]   (uniform LDS reads -> broadcast)
    float rad[4][N_MAX];
    #pragma unroll
    for (int l = 0; l < 4; ++l) {
        #pragma unroll
        for (int n = 0; n < N_MAX; ++n) {
            float a = 0.0f;
            #pragma unroll
            for (int b = 0; b < N_BASIS; ++b)
                a = fmaf(phi[b], sW[l * 96 + b * 8 + n], a);
            rad[l][n] = a;
        }
    }

    const int c = cidx[e];
    const int s = sidx[e];
    float* op = out + (size_t)c * 512 + s * 8;

    #pragma unroll
    for (int L = 0; L < 16; ++L) {
        const int l = (L == 0) ? 0 : (L < 4) ? 1 : (L < 9) ? 2 : 3;
        const float shv = sh[L];
        #pragma unroll
        for (int n = 0; n < N_MAX; ++n)
            atomicAdd(op + L * 32 + n, shv * rad[l][n]);
    }
}

extern "C" void kernel_launch(void* const* d_in, const int* in_sizes, int n_in,
                              void* d_out, int out_size, void* d_ws, size_t ws_size,
                              hipStream_t stream) {
    const float* vectors = (const float*)d_in[0];
    const float* rw      = (const float*)d_in[1];
    const int*   cidx    = (const int*)d_in[2];
    const int*   sidx    = (const int*)d_in[3];
    float*       out     = (float*)d_out;

    hipMemsetAsync(out, 0, (size_t)out_size * sizeof(float), stream);

    dim3 grid((N_EDGES + 255) / 256), block(256);
    hipLaunchKernelGGL(sph_exp_kernel, grid, block, 0, stream,
                       vectors, rw, cidx, sidx, out);
}

// Round 2
// 243.645 us; speedup vs baseline: 27.8986x; 27.8986x over previous
//
#include <hip/hip_runtime.h>
#include <math.h>

#define N_EDGES   1048576
#define N_SEG     131072        // 32768 centers * 4 species
#define N_BASIS   12
// out[c*512 + L*32 + s*8 + n], L in [0,16)

// ---------------- workspace layout ----------------
// counts  : int[131072]             @ 0         (512 KB)
// offsets : int[131072]             @ 524288    (512 KB)
// cursors : int[131072]             @ 1048576   (512 KB)
// bsums   : int[512]                @ 1572864   (2 KB)
// sorted  : float4[1048576]         @ 1574912   (16 MB)
#define WS_COUNTS   0
#define WS_OFFSETS  524288
#define WS_CURSORS  1048576
#define WS_BSUMS    1572864
#define WS_SORTED   1574912
#define WS_NEEDED   (1574912 + 16777216)

__device__ __forceinline__ void compute_edge(float x, float y, float z,
                                             float* __restrict__ ph,   // 12: sin(k*t), unscaled
                                             float* __restrict__ sh,   // 16
                                             float& scale)             // NORM/r
{
    const float r2    = fmaf(x, x, fmaf(y, y, z * z)) + 1e-12f;
    const float inv_r = rsqrtf(r2);
    const float r     = r2 * inv_r;
    x *= inv_r; y *= inv_r; z *= inv_r;

    const float t = 0.6283185307179586f * r;   // pi/5 * r
    float s1, c1;
    __sincosf(t, &s1, &c1);
    const float twoc = 2.0f * c1;
    float skm1 = 0.0f, sk = s1;                // sin(0), sin(t)
    #pragma unroll
    for (int b = 0; b < N_BASIS; ++b) {
        ph[b] = sk;
        const float nxt = fmaf(twoc, sk, -skm1);
        skm1 = sk; sk = nxt;
    }
    scale = 0.17677669529663687f * inv_r;      // (1/sqrt(32)) / r

    const float x2 = x * x, y2 = y * y, z2 = z * z;
    sh[0]  = 0.28209479177387814f;
    sh[1]  = 0.4886025119029199f * y;
    sh[2]  = 0.4886025119029199f * z;
    sh[3]  = 0.4886025119029199f * x;
    sh[4]  = 1.0925484305920792f * x * y;
    sh[5]  = 1.0925484305920792f * y * z;
    sh[6]  = 0.31539156525252005f * (3.0f * z2 - 1.0f);
    sh[7]  = 1.0925484305920792f * x * z;
    sh[8]  = 0.5462742152960396f * (x2 - y2);
    sh[9]  = 0.5900435899266435f * y * (3.0f * x2 - y2);
    sh[10] = 2.890611442640554f  * x * y * z;
    sh[11] = 0.4570457994644658f * y * (5.0f * z2 - 1.0f);
    sh[12] = 0.3731763325901154f * (5.0f * z2 * z - 3.0f * z);
    sh[13] = 0.4570457994644658f * x * (5.0f * z2 - 1.0f);
    sh[14] = 1.445305721320277f  * z * (x2 - y2);
    sh[15] = 0.5900435899266435f * x * (x2 - y2);
}

// ---------- pass 1: histogram ----------
__global__ __launch_bounds__(256) void hist_kernel(
    const int* __restrict__ cidx, const int* __restrict__ sidx,
    int* __restrict__ counts)
{
    const int e = blockIdx.x * 256 + threadIdx.x;
    if (e >= N_EDGES) return;
    atomicAdd(&counts[cidx[e] * 4 + sidx[e]], 1);
}

// ---------- pass 2a: per-block exclusive scan ----------
__global__ __launch_bounds__(256) void scan1_kernel(
    const int* __restrict__ counts, int* __restrict__ offsets,
    int* __restrict__ bsums)
{
    __shared__ int tmp[256];
    const int t = threadIdx.x;
    const int i = blockIdx.x * 256 + t;
    const int orig = counts[i];
    tmp[t] = orig;
    __syncthreads();
    #pragma unroll
    for (int d = 1; d < 256; d <<= 1) {
        const int v = (t >= d) ? tmp[t - d] : 0;
        __syncthreads();
        tmp[t] += v;
        __syncthreads();
    }
    offsets[i] = tmp[t] - orig;                // exclusive
    if (t == 255) bsums[blockIdx.x] = tmp[255];
}

// ---------- pass 2b: scan of block sums (512 elems, 1 block) ----------
__global__ __launch_bounds__(512) void scan2_kernel(int* __restrict__ bsums)
{
    __shared__ int tmp[512];
    const int t = threadIdx.x;
    const int orig = bsums[t];
    tmp[t] = orig;
    __syncthreads();
    #pragma unroll
    for (int d = 1; d < 512; d <<= 1) {
        const int v = (t >= d) ? tmp[t - d] : 0;
        __syncthreads();
        tmp[t] += v;
        __syncthreads();
    }
    bsums[t] = tmp[t] - orig;                  // exclusive
}

// ---------- pass 2c: add block offsets, init cursors ----------
__global__ __launch_bounds__(256) void scan3_kernel(
    int* __restrict__ offsets, const int* __restrict__ bsums,
    int* __restrict__ cursors)
{
    const int i = blockIdx.x * 256 + threadIdx.x;
    const int off = offsets[i] + bsums[blockIdx.x];
    offsets[i] = off;
    cursors[i] = off;
}

// ---------- pass 3: scatter edge vectors into sorted order ----------
__global__ __launch_bounds__(256) void scatter_kernel(
    const float* __restrict__ vectors,
    const int* __restrict__ cidx, const int* __restrict__ sidx,
    int* __restrict__ cursors, float4* __restrict__ sorted)
{
    const int e = blockIdx.x * 256 + threadIdx.x;
    if (e >= N_EDGES) return;
    const float x = vectors[3 * e + 0];
    const float y = vectors[3 * e + 1];
    const float z = vectors[3 * e + 2];
    const int seg = cidx[e] * 4 + sidx[e];
    const int p = atomicAdd(&cursors[seg], 1);
    sorted[p] = make_float4(x, y, z, 0.0f);
}

// ---------- pass 4: per-segment gather; each output written exactly once ----------
__global__ __launch_bounds__(256) void gather_kernel(
    const float4* __restrict__ sorted,
    const int* __restrict__ offsets, const int* __restrict__ counts,
    const float* __restrict__ rw,    // (4,12,8)
    float* __restrict__ out)
{
    __shared__ float sW[384];
    for (int i = threadIdx.x; i < 384; i += 256) sW[i] = rw[i];
    __syncthreads();

    const int t   = threadIdx.x;
    const int n   = t & 7;                     // radial index owned by this thread
    const int seg = blockIdx.x * 32 + (t >> 3);
    const int c   = seg >> 2;
    const int s   = seg & 3;
    const int off = offsets[seg];
    const int cnt = counts[seg];

    float acc[16];
    #pragma unroll
    for (int L = 0; L < 16; ++L) acc[L] = 0.0f;

    for (int j = 0; j < cnt; ++j) {
        const float4 v = sorted[off + j];
        float ph[N_BASIS], sh[16], scale;
        compute_edge(v.x, v.y, v.z, ph, sh, scale);

        float rad[4];
        #pragma unroll
        for (int l = 0; l < 4; ++l) {
            float a = 0.0f;
            #pragma unroll
            for (int b = 0; b < N_BASIS; ++b)
                a = fmaf(ph[b], sW[l * 96 + b * 8 + n], a);
            rad[l] = a * scale;
        }
        #pragma unroll
        for (int L = 0; L < 16; ++L) {
            const int l = (L == 0) ? 0 : (L < 4) ? 1 : (L < 9) ? 2 : 3;
            acc[L] = fmaf(sh[L], rad[l], acc[L]);
        }
    }

    float* op = out + (size_t)c * 512 + s * 8 + n;
    #pragma unroll
    for (int L = 0; L < 16; ++L)
        op[L * 32] = acc[L];
}

// ---------- fallback: round-1 atomic kernel (used only if ws too small) ----------
__global__ __launch_bounds__(256) void atomic_kernel(
    const float* __restrict__ vectors, const float* __restrict__ rw,
    const int* __restrict__ cidx, const int* __restrict__ sidx,
    float* __restrict__ out)
{
    __shared__ float sW[384];
    for (int i = threadIdx.x; i < 384; i += 256) sW[i] = rw[i];
    __syncthreads();
    const int e = blockIdx.x * 256 + threadIdx.x;
    if (e >= N_EDGES) return;
    float ph[N_BASIS], sh[16], scale;
    compute_edge(vectors[3*e], vectors[3*e+1], vectors[3*e+2], ph, sh, scale);
    float rad[4][8];
    for (int l = 0; l < 4; ++l)
        for (int n = 0; n < 8; ++n) {
            float a = 0.0f;
            for (int b = 0; b < N_BASIS; ++b)
                a = fmaf(ph[b], sW[l * 96 + b * 8 + n], a);
            rad[l][n] = a * scale;
        }
    float* op = out + (size_t)cidx[e] * 512 + sidx[e] * 8;
    for (int L = 0; L < 16; ++L) {
        const int l = (L == 0) ? 0 : (L < 4) ? 1 : (L < 9) ? 2 : 3;
        for (int n = 0; n < 8; ++n)
            atomicAdd(op + L * 32 + n, sh[L] * rad[l][n]);
    }
}

extern "C" void kernel_launch(void* const* d_in, const int* in_sizes, int n_in,
                              void* d_out, int out_size, void* d_ws, size_t ws_size,
                              hipStream_t stream) {
    const float* vectors = (const float*)d_in[0];
    const float* rw      = (const float*)d_in[1];
    const int*   cidx    = (const int*)d_in[2];
    const int*   sidx    = (const int*)d_in[3];
    float*       out     = (float*)d_out;

    if (ws_size < (size_t)WS_NEEDED) {
        hipMemsetAsync(out, 0, (size_t)out_size * sizeof(float), stream);
        hipLaunchKernelGGL(atomic_kernel, dim3(N_EDGES / 256), dim3(256), 0, stream,
                           vectors, rw, cidx, sidx, out);
        return;
    }

    char* ws = (char*)d_ws;
    int*    counts  = (int*)(ws + WS_COUNTS);
    int*    offsets = (int*)(ws + WS_OFFSETS);
    int*    cursors = (int*)(ws + WS_CURSORS);
    int*    bsums   = (int*)(ws + WS_BSUMS);
    float4* sorted  = (float4*)(ws + WS_SORTED);

    hipMemsetAsync(counts, 0, N_SEG * sizeof(int), stream);

    hipLaunchKernelGGL(hist_kernel,    dim3(N_EDGES / 256), dim3(256), 0, stream, cidx, sidx, counts);
    hipLaunchKernelGGL(scan1_kernel,   dim3(N_SEG / 256),   dim3(256), 0, stream, counts, offsets, bsums);
    hipLaunchKernelGGL(scan2_kernel,   dim3(1),             dim3(512), 0, stream, bsums);
    hipLaunchKernelGGL(scan3_kernel,   dim3(N_SEG / 256),   dim3(256), 0, stream, offsets, bsums, cursors);
    hipLaunchKernelGGL(scatter_kernel, dim3(N_EDGES / 256), dim3(256), 0, stream, vectors, cidx, sidx, cursors, sorted);
    hipLaunchKernelGGL(gather_kernel,  dim3(N_SEG / 32),    dim3(256), 0, stream, sorted, offsets, counts, rw, out);
}

// Round 3
// 173.409 us; speedup vs baseline: 39.1985x; 1.4050x over previous
//
#include <hip/hip_runtime.h>
#include <math.h>

#define N_EDGES   1048576
#define N_SEG     131072        // 32768 centers * 4 species
#define N_BUCKET  1024          // bucket = seg >> 7 (128 segs / bucket)
#define SEG_PER_B 128
#define N_BASIS   12
#define CAP       1536          // LDS staging capacity per bucket (Poisson mean 1024)
// out[c*512 + L*32 + s*8 + n], L in [0,16)

// ---------------- workspace layout ----------------
#define WS_COUNTS   0                       // int[1024]
#define WS_OFFSETS  4096                    // int[1024]
#define WS_CURSORS  8192                    // int[1024]
#define WS_SORTED   12288                   // float4[1048576]  (16 MB)
#define WS_NEEDED   (12288 + 16777216)

__device__ __forceinline__ void compute_edge(float x, float y, float z,
                                             float* __restrict__ ph,   // 12 unscaled sines
                                             float* __restrict__ sh,   // 16
                                             float& scale)             // NORM/r
{
    const float r2    = fmaf(x, x, fmaf(y, y, z * z)) + 1e-12f;
    const float inv_r = rsqrtf(r2);
    const float r     = r2 * inv_r;
    x *= inv_r; y *= inv_r; z *= inv_r;

    const float t = 0.6283185307179586f * r;   // pi/5 * r
    float s1, c1;
    __sincosf(t, &s1, &c1);
    const float twoc = 2.0f * c1;
    float skm1 = 0.0f, sk = s1;
    #pragma unroll
    for (int b = 0; b < N_BASIS; ++b) {
        ph[b] = sk;
        const float nxt = fmaf(twoc, sk, -skm1);
        skm1 = sk; sk = nxt;
    }
    scale = 0.17677669529663687f * inv_r;      // (1/sqrt(32)) / r

    const float x2 = x * x, y2 = y * y, z2 = z * z;
    sh[0]  = 0.28209479177387814f;
    sh[1]  = 0.4886025119029199f * y;
    sh[2]  = 0.4886025119029199f * z;
    sh[3]  = 0.4886025119029199f * x;
    sh[4]  = 1.0925484305920792f * x * y;
    sh[5]  = 1.0925484305920792f * y * z;
    sh[6]  = 0.31539156525252005f * (3.0f * z2 - 1.0f);
    sh[7]  = 1.0925484305920792f * x * z;
    sh[8]  = 0.5462742152960396f * (x2 - y2);
    sh[9]  = 0.5900435899266435f * y * (3.0f * x2 - y2);
    sh[10] = 2.890611442640554f  * x * y * z;
    sh[11] = 0.4570457994644658f * y * (5.0f * z2 - 1.0f);
    sh[12] = 0.3731763325901154f * (5.0f * z2 * z - 3.0f * z);
    sh[13] = 0.4570457994644658f * x * (5.0f * z2 - 1.0f);
    sh[14] = 1.445305721320277f  * z * (x2 - y2);
    sh[15] = 0.5900435899266435f * x * (x2 - y2);
}

// ---------- A1: coarse histogram (LDS-aggregated) ----------
__global__ __launch_bounds__(256) void hist_kernel(
    const int* __restrict__ cidx, const int* __restrict__ sidx,
    int* __restrict__ counts)
{
    __shared__ int h[N_BUCKET];
    const int t = threadIdx.x;
    #pragma unroll
    for (int i = t; i < N_BUCKET; i += 256) h[i] = 0;
    __syncthreads();
    const int base = blockIdx.x * 4096;
    #pragma unroll
    for (int k = 0; k < 16; ++k) {
        const int e = base + k * 256 + t;
        const int seg = (cidx[e] << 2) | sidx[e];
        atomicAdd(&h[seg >> 7], 1);
    }
    __syncthreads();
    #pragma unroll
    for (int i = t; i < N_BUCKET; i += 256)
        if (h[i]) atomicAdd(&counts[i], h[i]);
}

// ---------- scan over 1024 bucket counts (one block) ----------
__global__ __launch_bounds__(1024) void scan_kernel(
    const int* __restrict__ counts, int* __restrict__ offsets,
    int* __restrict__ cursors)
{
    __shared__ int tmp[N_BUCKET];
    const int t = threadIdx.x;
    const int orig = counts[t];
    tmp[t] = orig;
    __syncthreads();
    #pragma unroll
    for (int d = 1; d < N_BUCKET; d <<= 1) {
        const int v = (t >= d) ? tmp[t - d] : 0;
        __syncthreads();
        tmp[t] += v;
        __syncthreads();
    }
    const int off = tmp[t] - orig;
    offsets[t] = off;
    cursors[t] = off;
}

// ---------- A2: coarse partition with per-block chunk reservation ----------
__global__ __launch_bounds__(256) void partition_kernel(
    const float* __restrict__ vectors,
    const int* __restrict__ cidx, const int* __restrict__ sidx,
    int* __restrict__ cursors, float4* __restrict__ sorted)
{
    __shared__ int bhist[N_BUCKET];
    __shared__ int bbase[N_BUCKET];
    __shared__ int lcnt[N_BUCKET];
    const int t = threadIdx.x;
    #pragma unroll
    for (int i = t; i < N_BUCKET; i += 256) bhist[i] = 0;
    __syncthreads();

    const int base = blockIdx.x * 4096;
    int segs[16];
    #pragma unroll
    for (int k = 0; k < 16; ++k) {
        const int e = base + k * 256 + t;
        segs[k] = (cidx[e] << 2) | sidx[e];
        atomicAdd(&bhist[segs[k] >> 7], 1);
    }
    __syncthreads();

    // reserve one contiguous chunk per bucket for this block
    #pragma unroll
    for (int i = t; i < N_BUCKET; i += 256) {
        const int c = bhist[i];
        if (c) bbase[i] = atomicAdd(&cursors[i], c);
        lcnt[i] = 0;
    }
    __syncthreads();

    #pragma unroll
    for (int k = 0; k < 16; ++k) {
        const int e = base + k * 256 + t;
        const int seg = segs[k];
        const int bkt = seg >> 7;
        const int pos = bbase[bkt] + atomicAdd(&lcnt[bkt], 1);
        sorted[pos] = make_float4(vectors[3 * e], vectors[3 * e + 1],
                                  vectors[3 * e + 2],
                                  __int_as_float(seg & (SEG_PER_B - 1)));
    }
}

// ---------- B: per-bucket LDS counting-sort + compute; each output written once ----------
__global__ __launch_bounds__(256) void compute_kernel(
    const float4* __restrict__ sorted,
    const int* __restrict__ offsets, const int* __restrict__ counts,
    const float* __restrict__ rw,    // (4,12,8)
    float* __restrict__ out)
{
    __shared__ float4 pay[CAP];                 // 24 KB
    __shared__ unsigned short ord[CAP];         // 3 KB
    __shared__ int shist[SEG_PER_B];
    __shared__ int soff[SEG_PER_B];
    __shared__ int scur[SEG_PER_B];
    __shared__ float sW[384];

    const int t = threadIdx.x;
    const int b = blockIdx.x;
    for (int i = t; i < 384; i += 256) sW[i] = rw[i];
    if (t < SEG_PER_B) shist[t] = 0;

    const int off = offsets[b];
    const int cnt = counts[b];
    const int cntc = (cnt < CAP) ? cnt : CAP;
    __syncthreads();

    // stage payload + histogram by local segment
    for (int i = t; i < cntc; i += 256) {
        const float4 v = sorted[off + i];
        pay[i] = v;
        atomicAdd(&shist[__float_as_int(v.w)], 1);
    }
    __syncthreads();

    // exclusive scan of shist (128) using threads 0..127
    if (t < SEG_PER_B) soff[t] = shist[t];
    __syncthreads();
    #pragma unroll
    for (int d = 1; d < SEG_PER_B; d <<= 1) {
        int v = 0;
        if (t >= d && t < SEG_PER_B) v = soff[t - d];
        __syncthreads();
        if (t < SEG_PER_B) soff[t] += v;
        __syncthreads();
    }
    if (t < SEG_PER_B) {
        const int ex = soff[t] - shist[t];
        soff[t] = ex;
        scur[t] = ex;
    }
    __syncthreads();

    // build sorted order
    for (int i = t; i < cntc; i += 256) {
        const int sl = __float_as_int(pay[i].w);
        const int r = atomicAdd(&scur[sl], 1);
        ord[r] = (unsigned short)i;
    }
    __syncthreads();

    // compute: 32 (seg) x 8 (n) per round, 4 rounds
    const int n = t & 7;
    #pragma unroll 1
    for (int chunk = 0; chunk < 4; ++chunk) {
        const int sl = chunk * 32 + (t >> 3);
        const int js = soff[sl];
        const int je = js + shist[sl];

        float acc[16];
        #pragma unroll
        for (int L = 0; L < 16; ++L) acc[L] = 0.0f;

        for (int j = js; j < je; ++j) {
            const float4 v = pay[ord[j]];
            float ph[N_BASIS], sh[16], scale;
            compute_edge(v.x, v.y, v.z, ph, sh, scale);
            float rad[4];
            #pragma unroll
            for (int l = 0; l < 4; ++l) {
                float a = 0.0f;
                #pragma unroll
                for (int bb = 0; bb < N_BASIS; ++bb)
                    a = fmaf(ph[bb], sW[l * 96 + bb * 8 + n], a);
                rad[l] = a * scale;
            }
            #pragma unroll
            for (int L = 0; L < 16; ++L) {
                const int l = (L == 0) ? 0 : (L < 4) ? 1 : (L < 9) ? 2 : 3;
                acc[L] = fmaf(sh[L], rad[l], acc[L]);
            }
        }
        // overflow edges (cnt > CAP): read from global, filter by segment (rare/never)
        for (int j = CAP; j < cnt; ++j) {
            const float4 v = sorted[off + j];
            if (__float_as_int(v.w) != sl) continue;
            float ph[N_BASIS], sh[16], scale;
            compute_edge(v.x, v.y, v.z, ph, sh, scale);
            float rad[4];
            #pragma unroll
            for (int l = 0; l < 4; ++l) {
                float a = 0.0f;
                #pragma unroll
                for (int bb = 0; bb < N_BASIS; ++bb)
                    a = fmaf(ph[bb], sW[l * 96 + bb * 8 + n], a);
                rad[l] = a * scale;
            }
            #pragma unroll
            for (int L = 0; L < 16; ++L) {
                const int l = (L == 0) ? 0 : (L < 4) ? 1 : (L < 9) ? 2 : 3;
                acc[L] = fmaf(sh[L], rad[l], acc[L]);
            }
        }

        const int seg = b * SEG_PER_B + sl;
        float* op = out + (size_t)(seg >> 2) * 512 + (seg & 3) * 8 + n;
        #pragma unroll
        for (int L = 0; L < 16; ++L)
            op[L * 32] = acc[L];
    }
}

// ---------- fallback: atomic kernel (used only if ws too small) ----------
__global__ __launch_bounds__(256) void atomic_kernel(
    const float* __restrict__ vectors, const float* __restrict__ rw,
    const int* __restrict__ cidx, const int* __restrict__ sidx,
    float* __restrict__ out)
{
    __shared__ float sW[384];
    for (int i = threadIdx.x; i < 384; i += 256) sW[i] = rw[i];
    __syncthreads();
    const int e = blockIdx.x * 256 + threadIdx.x;
    if (e >= N_EDGES) return;
    float ph[N_BASIS], sh[16], scale;
    compute_edge(vectors[3*e], vectors[3*e+1], vectors[3*e+2], ph, sh, scale);
    float rad[4][8];
    for (int l = 0; l < 4; ++l)
        for (int n = 0; n < 8; ++n) {
            float a = 0.0f;
            for (int b = 0; b < N_BASIS; ++b)
                a = fmaf(ph[b], sW[l * 96 + b * 8 + n], a);
            rad[l][n] = a * scale;
        }
    float* op = out + (size_t)cidx[e] * 512 + sidx[e] * 8;
    for (int L = 0; L < 16; ++L) {
        const int l = (L == 0) ? 0 : (L < 4) ? 1 : (L < 9) ? 2 : 3;
        for (int n = 0; n < 8; ++n)
            atomicAdd(op + L * 32 + n, sh[L] * rad[l][n]);
    }
}

extern "C" void kernel_launch(void* const* d_in, const int* in_sizes, int n_in,
                              void* d_out, int out_size, void* d_ws, size_t ws_size,
                              hipStream_t stream) {
    const float* vectors = (const float*)d_in[0];
    const float* rw      = (const float*)d_in[1];
    const int*   cidx    = (const int*)d_in[2];
    const int*   sidx    = (const int*)d_in[3];
    float*       out     = (float*)d_out;

    if (ws_size < (size_t)WS_NEEDED) {
        hipMemsetAsync(out, 0, (size_t)out_size * sizeof(float), stream);
        hipLaunchKernelGGL(atomic_kernel, dim3(N_EDGES / 256), dim3(256), 0, stream,
                           vectors, rw, cidx, sidx, out);
        return;
    }

    char* ws = (char*)d_ws;
    int*    counts  = (int*)(ws + WS_COUNTS);
    int*    offsets = (int*)(ws + WS_OFFSETS);
    int*    cursors = (int*)(ws + WS_CURSORS);
    float4* sorted  = (float4*)(ws + WS_SORTED);

    hipMemsetAsync(counts, 0, N_BUCKET * sizeof(int), stream);

    hipLaunchKernelGGL(hist_kernel,      dim3(N_EDGES / 4096), dim3(256),  0, stream, cidx, sidx, counts);
    hipLaunchKernelGGL(scan_kernel,      dim3(1),              dim3(1024), 0, stream, counts, offsets, cursors);
    hipLaunchKernelGGL(partition_kernel, dim3(N_EDGES / 4096), dim3(256),  0, stream, vectors, cidx, sidx, cursors, sorted);
    hipLaunchKernelGGL(compute_kernel,   dim3(N_BUCKET),       dim3(256),  0, stream, sorted, offsets, counts, rw, out);
}